// Round 1
// 104.468 us; speedup vs baseline: 1.1220x; 1.1220x over previous
//
#include <hip/hip_runtime.h>
#include <math.h>

// MultiWindowAttention B=4,L=2048,H=8,E=D=64 fp32; w = 32<<(h&3).
// Round 7: per-CU load balancing.
//   R6 counters: MfmaUtil 6%, VALUBusy 22%, Occ 23% -> nothing is busy.
//   Same-CU blocks are spaced 256 apart (XCD=gid&7, CU=(gid>>3)&31 round
//   robin); old h-map gave them IDENTICAL heads -> CUs with 4x w=256 blocks
//   (36 tiles) gate the kernel while w=32 CUs (9 tiles) idle.
//   New bijection: b=gid>>8, c=gid&255, it=c>>3, h=(c2<<2)|((b+c)&3):
//     - blocks {c,c+256,c+512,c+768} (one CU) cover all 4 window classes
//       -> 3+3+5+9 = 20 tiles per CU, balanced.
//     - all blocks of one (b,h) slice share gid&7 -> same XCD -> window
//       overlap re-reads are L2-local.
//   Also: V^T staged with 2x ds_write_b128 (was 8x b32 at 8-way conflict),
//   and softmax scale folded into the Q bf16 pack (2^-3, exact).
//   Everything else identical to R6 (S^T trick, P in regs, dbuf LDS).

#define LL 2048
#define HH 8
#define EE 64
#define DD 64
#define RS (HH * EE)   // 512 floats between consecutive seq positions

typedef __attribute__((ext_vector_type(8))) short short8;
typedef __attribute__((ext_vector_type(4))) float floatx4;
typedef __attribute__((ext_vector_type(4))) _Float16 half4;
typedef __attribute__((ext_vector_type(2))) __fp16 fp16x2;   // cvt_pkrtz return type

static __device__ __forceinline__ unsigned f2bf(float f) {
    union { float f; unsigned u; } v; v.f = f;
    return (v.u + 0x7fff + ((v.u >> 16) & 1)) >> 16;   // RNE
}
static __device__ __forceinline__ unsigned pack2(float a, float b) {
    return f2bf(a) | (f2bf(b) << 16);
}
static __device__ __forceinline__ unsigned packh2(float a, float b) {
    union { fp16x2 h; unsigned u; } v;
    v.h = __builtin_amdgcn_cvt_pkrtz(a, b);
    return v.u;
}

__global__ __launch_bounds__(256, 4) void mwa_r7(
    const float* __restrict__ Q,
    const float* __restrict__ K,
    const float* __restrict__ V,
    float* __restrict__ O)
{
    const int tid  = threadIdx.x;
    const int lane = tid & 63;
    const int wv   = tid >> 6;
    const int quad = lane >> 4;
    const int l15  = lane & 15;

    // ---- balanced task decode (see header comment) ----
    const int gid = blockIdx.x;
    const int kb  = gid >> 8;                  // 0..3 -> b
    const int c   = gid & 255;
    const int b   = kb;
    const int it  = c >> 3;                    // 0..31
    const int h   = (((c >> 2) & 1) << 2) | ((kb + c) & 3);
    const int i0  = it << 6;
    const int w   = 32 << (h & 3);

    alignas(16) __shared__ short sK [2][4096];     // K frag-linear, bf16 (8KB each)
    alignas(16) __shared__ short sVt[2][64 * 72];  // V^T [d][j], f16, ld=72

    const float* Qb = Q + ((size_t)b * LL * HH + h) * EE;
    const float* Kb = K + ((size_t)b * LL * HH + h) * EE;
    const float* Vb = V + ((size_t)b * LL * HH + h) * DD;
    float*       Ob = O + ((size_t)b * LL * HH + h) * DD;

    // ---- stage Q (bf16, ld=72, pre-scaled by 1/8) into sK region, grab B-frags ----
    {
        const float sc = 0.125f;   // 2^-3: exact in bf16, folds softmax scale away
        const int row = tid >> 2, cc = (tid & 3) << 4;
        const float4* src = (const float4*)(Qb + (size_t)(i0 + row) * RS + cc);
        float4 f0 = src[0], f1 = src[1], f2 = src[2], f3 = src[3];
        uint4 u0 = { pack2(sc*f0.x,sc*f0.y), pack2(sc*f0.z,sc*f0.w),
                     pack2(sc*f1.x,sc*f1.y), pack2(sc*f1.z,sc*f1.w) };
        uint4 u1 = { pack2(sc*f2.x,sc*f2.y), pack2(sc*f2.z,sc*f2.w),
                     pack2(sc*f3.x,sc*f3.y), pack2(sc*f3.z,sc*f3.w) };
        uint4* dst = (uint4*)&sK[0][row * 72 + cc];    // spans into sK[1]; OK pre-loop
        dst[0] = u0; dst[1] = u1;
    }
    __syncthreads();
    short8 qf0, qf1;
    {
        const short* p = &sK[0][(wv * 16 + l15) * 72 + quad * 8];
        qf0 = *(const short8*)p;
        qf1 = *(const short8*)(p + 32);
    }
    __syncthreads();   // all Q-frag reads done before K staging overwrites

    const int jt_lo = max(0, i0 - w) >> 6;
    const int jt_hi = min(LL - 1, i0 + 63 + w) >> 6;

    // ---- stage first tile into buffer 0 ----
    {
        const int j0 = jt_lo << 6;
        const int row = tid >> 2, cc = (tid & 3) << 4;
        const float4* src = (const float4*)(Kb + (size_t)(j0 + row) * RS + cc);
        float4 f0 = src[0], f1 = src[1], f2 = src[2], f3 = src[3];
        float vv[16];
#pragma unroll
        for (int rr = 0; rr < 16; ++rr)
            vv[rr] = Vb[(size_t)(j0 + wv * 16 + rr) * RS + lane];

        uint4 u0 = { pack2(f0.x,f0.y), pack2(f0.z,f0.w), pack2(f1.x,f1.y), pack2(f1.z,f1.w) };
        uint4 u1 = { pack2(f2.x,f2.y), pack2(f2.z,f2.w), pack2(f3.x,f3.y), pack2(f3.z,f3.w) };
        const int jtw = row >> 4, l15w = row & 15, ks = cc >> 5, q0 = (cc >> 3) & 3;
        *(uint4*)&sK[0][(((jtw * 2 + ks) * 4 + q0    ) * 16 + l15w) * 8] = u0;
        *(uint4*)&sK[0][(((jtw * 2 + ks) * 4 + q0 + 1) * 16 + l15w) * 8] = u1;

        uint4 w0 = { packh2(vv[0],vv[1]),  packh2(vv[2],vv[3]),
                     packh2(vv[4],vv[5]),  packh2(vv[6],vv[7]) };
        uint4 w1 = { packh2(vv[8],vv[9]),  packh2(vv[10],vv[11]),
                     packh2(vv[12],vv[13]), packh2(vv[14],vv[15]) };
        *(uint4*)&sVt[0][lane * 72 + wv * 16    ] = w0;
        *(uint4*)&sVt[0][lane * 72 + wv * 16 + 8] = w1;
    }
    __syncthreads();

    floatx4 acc[4] = {};
    float lsum = 0.f;
    const int iq = i0 + wv * 16 + l15;   // this lane's query row (q = l15)

    for (int jt = jt_lo; jt <= jt_hi; ++jt) {
        const int cur = (jt - jt_lo) & 1;
        const int nxt = cur ^ 1;
        const bool more = jt < jt_hi;
        const int j0 = jt << 6;

        // ---- prefetch next tile into registers ----
        float4 kf0, kf1, kf2, kf3;
        float vv[16];
        const int rowp = tid >> 2, cp = (tid & 3) << 4;
        if (more) {
            const int jn = (jt + 1) << 6;
            const float4* src = (const float4*)(Kb + (size_t)(jn + rowp) * RS + cp);
            kf0 = src[0]; kf1 = src[1]; kf2 = src[2]; kf3 = src[3];
#pragma unroll
            for (int rr = 0; rr < 16; ++rr)
                vv[rr] = Vb[(size_t)(jn + wv * 16 + rr) * RS + lane];
        }

        // ---- S^T = K.Q^T (Q pre-scaled), then exp -> P^T (stays in registers) ----
        const bool full = ((i0 + 63 - j0) <= w) && ((j0 + 63 - i0) <= w);
        half4 pf[4];
#pragma unroll
        for (int t4 = 0; t4 < 4; ++t4) {
            const short* kp = &sK[cur][1024 * t4 + 128 * quad + 8 * l15];
            short8 k0 = *(const short8*)kp;
            short8 k1 = *(const short8*)(kp + 512);
            floatx4 st = {};
            st = __builtin_amdgcn_mfma_f32_16x16x32_bf16(k0, qf0, st, 0, 0, 0);
            st = __builtin_amdgcn_mfma_f32_16x16x32_bf16(k1, qf1, st, 0, 0, 0);

            float p[4];
            const int jb = j0 + t4 * 16 + quad * 4;
#pragma unroll
            for (int r = 0; r < 4; ++r) {
                float x = st[r];
                if (!full) {
                    const int di = iq - (jb + r);
                    x = (di <= w && di >= -w) ? x : -INFINITY;
                }
                p[r] = __expf(x);
                lsum += p[r];
            }
            union { half4 v; unsigned u[2]; } pu;
            pu.u[0] = packh2(p[0], p[1]);
            pu.u[1] = packh2(p[2], p[3]);
            pf[t4] = pu.v;
        }

        // ---- O += P.V  (16x16x16 f16; A = P from regs, B = V^T from LDS) ----
#pragma unroll
        for (int nt = 0; nt < 4; ++nt) {
            const short* vbase = &sVt[cur][(nt * 16 + l15) * 72];
#pragma unroll
            for (int t4 = 0; t4 < 4; ++t4) {
                half4 vf = *(const half4*)(vbase + t4 * 16 + quad * 4);
                acc[nt] = __builtin_amdgcn_mfma_f32_16x16x16f16(pf[t4], vf, acc[nt], 0, 0, 0);
            }
        }

        // ---- write next tile to LDS ----
        if (more) {
            uint4 u0 = { pack2(kf0.x,kf0.y), pack2(kf0.z,kf0.w), pack2(kf1.x,kf1.y), pack2(kf1.z,kf1.w) };
            uint4 u1 = { pack2(kf2.x,kf2.y), pack2(kf2.z,kf2.w), pack2(kf3.x,kf3.y), pack2(kf3.z,kf3.w) };
            const int jtw = rowp >> 4, l15w = rowp & 15, ks = cp >> 5, q0 = (cp >> 3) & 3;
            *(uint4*)&sK[nxt][(((jtw * 2 + ks) * 4 + q0    ) * 16 + l15w) * 8] = u0;
            *(uint4*)&sK[nxt][(((jtw * 2 + ks) * 4 + q0 + 1) * 16 + l15w) * 8] = u1;

            uint4 w0 = { packh2(vv[0],vv[1]),  packh2(vv[2],vv[3]),
                         packh2(vv[4],vv[5]),  packh2(vv[6],vv[7]) };
            uint4 w1 = { packh2(vv[8],vv[9]),  packh2(vv[10],vv[11]),
                         packh2(vv[12],vv[13]), packh2(vv[14],vv[15]) };
            *(uint4*)&sVt[nxt][lane * 72 + wv * 16    ] = w0;
            *(uint4*)&sVt[nxt][lane * 72 + wv * 16 + 8] = w1;
        }
        __syncthreads();
    }

    // ---- epilogue: finish l, normalize, store ----
    lsum += __shfl_xor(lsum, 16, 64);
    lsum += __shfl_xor(lsum, 32, 64);
    float rinv[4];
#pragma unroll
    for (int r = 0; r < 4; ++r) {
        const float lr = __shfl(lsum, quad * 4 + r, 64);
        rinv[r] = 1.0f / lr;
    }
#pragma unroll
    for (int nt = 0; nt < 4; ++nt) {
#pragma unroll
        for (int r = 0; r < 4; ++r) {
            Ob[(size_t)(i0 + wv * 16 + quad * 4 + r) * RS + nt * 16 + l15]
                = acc[nt][r] * rinv[r];
        }
    }
}

extern "C" void kernel_launch(void* const* d_in, const int* in_sizes, int n_in,
                              void* d_out, int out_size, void* d_ws, size_t ws_size,
                              hipStream_t stream)
{
    const float* Q = (const float*)d_in[0];
    const float* K = (const float*)d_in[1];
    const float* V = (const float*)d_in[2];
    float* O = (float*)d_out;

    dim3 grid(4 * HH * (LL / 64)), block(256);   // 1024 blocks
    hipLaunchKernelGGL(mwa_r7, grid, block, 0, stream, Q, K, V, O);
}

// Round 2
// 103.995 us; speedup vs baseline: 1.1271x; 1.0045x over previous
//
#include <hip/hip_runtime.h>
#include <math.h>

// MultiWindowAttention B=4,L=2048,H=8,E=D=64 fp32; w = 32<<(h&3).
// Round 8: intra-block j-window split (2 groups x 4 waves) + LPT dispatch.
//   R7 left a serial tail: all 4 blocks/CU resident from t=0, and the w256
//   block (9-10 j-tiles) runs alone (1 wave/SIMD) for the last ~half of the
//   kernel. Split each i-tile's j-range across two 4-wave groups in one
//   512-thread block (group g takes tiles jt_lo+g, +2, ...), each group with
//   its own double-buffered sK/sVt (68 KB LDS -> 2 blocks/CU, 16 waves/CU).
//   Critical chain: 9.5 -> 5 visits. acc/lsum merged through LDS at the end.
//   Grid is LPT-ordered (w256 blocks first) so the now-active backfill keeps
//   every CU >=8 waves; gid&7 = b*2+hb keeps (b,h) slices XCD-local for L2.

#define LL 2048
#define HH 8
#define EE 64
#define DD 64
#define RS (HH * EE)   // 512 floats between consecutive seq positions

typedef __attribute__((ext_vector_type(8))) short short8;
typedef __attribute__((ext_vector_type(4))) float floatx4;
typedef __attribute__((ext_vector_type(4))) _Float16 half4;
typedef __attribute__((ext_vector_type(2))) __fp16 fp16x2;   // cvt_pkrtz return type

static __device__ __forceinline__ unsigned f2bf(float f) {
    union { float f; unsigned u; } v; v.f = f;
    return (v.u + 0x7fff + ((v.u >> 16) & 1)) >> 16;   // RNE
}
static __device__ __forceinline__ unsigned pack2(float a, float b) {
    return f2bf(a) | (f2bf(b) << 16);
}
static __device__ __forceinline__ unsigned packh2(float a, float b) {
    union { fp16x2 h; unsigned u; } v;
    v.h = __builtin_amdgcn_cvt_pkrtz(a, b);
    return v.u;
}

__global__ __launch_bounds__(512, 4) void mwa_r8(
    const float* __restrict__ Q,
    const float* __restrict__ K,
    const float* __restrict__ V,
    float* __restrict__ O)
{
    const int tid  = threadIdx.x;
    const int lane = tid & 63;
    const int grp  = tid >> 8;          // j-split group 0/1
    const int tid8 = tid & 255;         // thread within group
    const int wv   = (tid >> 6) & 3;    // wave within group
    const int quad = lane >> 4;
    const int l15  = lane & 15;

    // ---- LPT task decode: class k=0 (w=256) dispatched first ... k=3 (w=32) last.
    //      gid&7 = b*2+hb for every it of a (b,h) slice -> XCD-local K/V re-reads.
    const int gid = blockIdx.x;
    const int k   = gid >> 8;          // window class, big first
    const int r   = gid & 255;
    const int it  = r >> 3;            // 0..31
    const int b   = (r >> 1) & 3;
    const int hb  = r & 1;
    const int h   = hb * 4 + (3 - k);
    const int i0  = it << 6;
    const int w   = 32 << (3 - k);

    alignas(16) __shared__ short sK [2][2][4096];     // [grp][buf] K frag-linear bf16 (32KB)
    alignas(16) __shared__ short sVt[2][2][64 * 72];  // [grp][buf] V^T [d][j] f16 ld=72 (36KB)

    const float* Qb = Q + ((size_t)b * LL * HH + h) * EE;
    const float* Kb = K + ((size_t)b * LL * HH + h) * EE;
    const float* Vb = V + ((size_t)b * LL * HH + h) * DD;
    float*       Ob = O + ((size_t)b * LL * HH + h) * DD;

    // ---- stage Q once (bf16, ld=72, pre-scaled by 1/8) into sK area; both groups share ----
    {
        const float sc = 0.125f;       // 2^-3: exact in bf16, folds softmax scale
        const int row = tid >> 3, cc = (tid & 7) << 3;   // 64 rows x 8 floats
        const float4* src = (const float4*)(Qb + (size_t)(i0 + row) * RS + cc);
        float4 f0 = src[0], f1 = src[1];
        uint4 u0 = { pack2(sc*f0.x,sc*f0.y), pack2(sc*f0.z,sc*f0.w),
                     pack2(sc*f1.x,sc*f1.y), pack2(sc*f1.z,sc*f1.w) };
        *(uint4*)&(((short*)sK)[row * 72 + cc]) = u0;
    }
    __syncthreads();
    short8 qf0, qf1;
    {
        const short* p = &(((short*)sK)[(wv * 16 + l15) * 72 + quad * 8]);
        qf0 = *(const short8*)p;
        qf1 = *(const short8*)(p + 32);
    }
    __syncthreads();   // Q-frag reads done before K staging overwrites

    const int jt_lo = max(0, i0 - w) >> 6;
    const int jt_hi = min(LL - 1, i0 + 63 + w) >> 6;
    const int n     = jt_hi - jt_lo + 1;          // always >= 2
    const int ng    = (n - grp + 1) >> 1;         // tiles for this group (ceil/floor)
    const int nIter = (n + 1) >> 1;               // lockstep iteration count

    // ---- stage this group's first tile into buffer 0 ----
    {
        const int j0 = (jt_lo + grp) << 6;
        const int row = tid8 >> 2, cc = (tid8 & 3) << 4;
        const float4* src = (const float4*)(Kb + (size_t)(j0 + row) * RS + cc);
        float4 f0 = src[0], f1 = src[1], f2 = src[2], f3 = src[3];
        float vv[16];
#pragma unroll
        for (int rr = 0; rr < 16; ++rr)
            vv[rr] = Vb[(size_t)(j0 + wv * 16 + rr) * RS + lane];

        uint4 u0 = { pack2(f0.x,f0.y), pack2(f0.z,f0.w), pack2(f1.x,f1.y), pack2(f1.z,f1.w) };
        uint4 u1 = { pack2(f2.x,f2.y), pack2(f2.z,f2.w), pack2(f3.x,f3.y), pack2(f3.z,f3.w) };
        const int jtw = row >> 4, l15w = row & 15, ks = cc >> 5, q0 = (cc >> 3) & 3;
        *(uint4*)&sK[grp][0][(((jtw * 2 + ks) * 4 + q0    ) * 16 + l15w) * 8] = u0;
        *(uint4*)&sK[grp][0][(((jtw * 2 + ks) * 4 + q0 + 1) * 16 + l15w) * 8] = u1;

        uint4 w0 = { packh2(vv[0],vv[1]),  packh2(vv[2],vv[3]),
                     packh2(vv[4],vv[5]),  packh2(vv[6],vv[7]) };
        uint4 w1 = { packh2(vv[8],vv[9]),  packh2(vv[10],vv[11]),
                     packh2(vv[12],vv[13]), packh2(vv[14],vv[15]) };
        *(uint4*)&sVt[grp][0][lane * 72 + wv * 16    ] = w0;
        *(uint4*)&sVt[grp][0][lane * 72 + wv * 16 + 8] = w1;
    }
    __syncthreads();

    floatx4 acc[4] = {};
    float lsum = 0.f;
    const int iq = i0 + wv * 16 + l15;   // this lane's query row (q = l15)

    for (int s = 0; s < nIter; ++s) {
        const int cur = s & 1;
        const int nxt = cur ^ 1;
        const bool act  = s < ng;          // group1 may idle on the last iteration
        const bool more = (s + 1) < ng;
        const int jt = jt_lo + grp + 2 * s;
        const int j0 = jt << 6;

        // ---- prefetch this group's next tile (jt+2) into registers ----
        float4 kf0, kf1, kf2, kf3;
        float vv[16];
        const int rowp = tid8 >> 2, cp = (tid8 & 3) << 4;
        if (more) {
            const int jn = (jt + 2) << 6;
            const float4* src = (const float4*)(Kb + (size_t)(jn + rowp) * RS + cp);
            kf0 = src[0]; kf1 = src[1]; kf2 = src[2]; kf3 = src[3];
#pragma unroll
            for (int rr = 0; rr < 16; ++rr)
                vv[rr] = Vb[(size_t)(jn + wv * 16 + rr) * RS + lane];
        }

        if (act) {
            // ---- S^T = K.Q^T (Q pre-scaled), exp -> P^T in registers ----
            const bool full = ((i0 + 63 - j0) <= w) && ((j0 + 63 - i0) <= w);
            half4 pf[4];
#pragma unroll
            for (int t4 = 0; t4 < 4; ++t4) {
                const short* kp = &sK[grp][cur][1024 * t4 + 128 * quad + 8 * l15];
                short8 k0 = *(const short8*)kp;
                short8 k1 = *(const short8*)(kp + 512);
                floatx4 st = {};
                st = __builtin_amdgcn_mfma_f32_16x16x32_bf16(k0, qf0, st, 0, 0, 0);
                st = __builtin_amdgcn_mfma_f32_16x16x32_bf16(k1, qf1, st, 0, 0, 0);

                float p[4];
                const int jb = j0 + t4 * 16 + quad * 4;
#pragma unroll
                for (int rr2 = 0; rr2 < 4; ++rr2) {
                    float x = st[rr2];
                    if (!full) {
                        const int di = iq - (jb + rr2);
                        x = (di <= w && di >= -w) ? x : -INFINITY;
                    }
                    p[rr2] = __expf(x);
                    lsum += p[rr2];
                }
                union { half4 v; unsigned u[2]; } pu;
                pu.u[0] = packh2(p[0], p[1]);
                pu.u[1] = packh2(p[2], p[3]);
                pf[t4] = pu.v;
            }

            // ---- O += P.V (A = P regs, B = V^T LDS) ----
#pragma unroll
            for (int nt = 0; nt < 4; ++nt) {
                const short* vbase = &sVt[grp][cur][(nt * 16 + l15) * 72];
#pragma unroll
                for (int t4 = 0; t4 < 4; ++t4) {
                    half4 vf = *(const half4*)(vbase + t4 * 16 + quad * 4);
                    acc[nt] = __builtin_amdgcn_mfma_f32_16x16x16f16(pf[t4], vf, acc[nt], 0, 0, 0);
                }
            }
        }

        // ---- write prefetched tile to the other buffer ----
        if (more) {
            uint4 u0 = { pack2(kf0.x,kf0.y), pack2(kf0.z,kf0.w), pack2(kf1.x,kf1.y), pack2(kf1.z,kf1.w) };
            uint4 u1 = { pack2(kf2.x,kf2.y), pack2(kf2.z,kf2.w), pack2(kf3.x,kf3.y), pack2(kf3.z,kf3.w) };
            const int jtw = rowp >> 4, l15w = rowp & 15, ks = cp >> 5, q0 = (cp >> 3) & 3;
            *(uint4*)&sK[grp][nxt][(((jtw * 2 + ks) * 4 + q0    ) * 16 + l15w) * 8] = u0;
            *(uint4*)&sK[grp][nxt][(((jtw * 2 + ks) * 4 + q0 + 1) * 16 + l15w) * 8] = u1;

            uint4 w0 = { packh2(vv[0],vv[1]),  packh2(vv[2],vv[3]),
                         packh2(vv[4],vv[5]),  packh2(vv[6],vv[7]) };
            uint4 w1 = { packh2(vv[8],vv[9]),  packh2(vv[10],vv[11]),
                         packh2(vv[12],vv[13]), packh2(vv[14],vv[15]) };
            *(uint4*)&sVt[grp][nxt][lane * 72 + wv * 16    ] = w0;
            *(uint4*)&sVt[grp][nxt][lane * 72 + wv * 16 + 8] = w1;
        }
        __syncthreads();
    }

    // ---- merge the two groups' partial acc / lsum through LDS ----
    lsum += __shfl_xor(lsum, 16, 64);
    lsum += __shfl_xor(lsum, 32, 64);      // per-lane: row-sum for q = wv*16+l15

    float* mrg = (float*)&sK[0][0][0];     // 16 KB acc merge area (sK no longer needed)
    float* lsA = (float*)&sVt[0][0][0];    // 64 floats lsum merge

    if (grp == 1) {
#pragma unroll
        for (int nt = 0; nt < 4; ++nt)
            *(floatx4*)&mrg[(tid8 * 4 + nt) * 4] = acc[nt];
        if (quad == 0) lsA[wv * 16 + l15] = lsum;
    }
    __syncthreads();

    if (grp == 0) {
        lsum += lsA[wv * 16 + l15];
#pragma unroll
        for (int nt = 0; nt < 4; ++nt) {
            floatx4 o = *(const floatx4*)&mrg[(tid8 * 4 + nt) * 4];
            acc[nt][0] += o[0]; acc[nt][1] += o[1];
            acc[nt][2] += o[2]; acc[nt][3] += o[3];
        }
        float rinv[4];
#pragma unroll
        for (int rr2 = 0; rr2 < 4; ++rr2) {
            const float lr = __shfl(lsum, quad * 4 + rr2, 64);
            rinv[rr2] = 1.0f / lr;
        }
#pragma unroll
        for (int nt = 0; nt < 4; ++nt) {
#pragma unroll
            for (int rr2 = 0; rr2 < 4; ++rr2) {
                Ob[(size_t)(i0 + wv * 16 + quad * 4 + rr2) * RS + nt * 16 + l15]
                    = acc[nt][rr2] * rinv[rr2];
            }
        }
    }
}

extern "C" void kernel_launch(void* const* d_in, const int* in_sizes, int n_in,
                              void* d_out, int out_size, void* d_ws, size_t ws_size,
                              hipStream_t stream)
{
    const float* Q = (const float*)d_in[0];
    const float* K = (const float*)d_in[1];
    const float* V = (const float*)d_in[2];
    float* O = (float*)d_out;

    dim3 grid(4 * HH * (LL / 64)), block(512);   // 1024 blocks, LPT-ordered
    hipLaunchKernelGGL(mwa_r8, grid, block, 0, stream, Q, K, V, O);
}

// Round 3
// 101.598 us; speedup vs baseline: 1.1537x; 1.0236x over previous
//
#include <hip/hip_runtime.h>
#include <math.h>

// MultiWindowAttention B=4,L=2048,H=8,E=D=64 fp32; w = 32<<(h&3).
// Round 9: 128-row i-tiles, 8 waves sharing one K/V staging.
//   R8 (j-split) was neutral -> scheduling is NOT the bottleneck; per-visit
//   memory service is (per round all groups fetch fresh 32KB tiles; R6's
//   9 rounds x ~5us/round matches 44us). So: amortize staging over 2x the
//   compute. Each block now covers 128 q-rows (8 waves x 16 rows), one
//   shared double-buffered K/V tile; staging per unit compute halves and
//   total visits drop 5120 -> 3072 (logical K/V traffic 164 -> 98 MB).
//   No j-split, no merge epilogue. 512 blocks x 512 threads, LDS 34 KB.
//   Mapping keeps (b,h)->XCD pinning (gid&7 fixed per slice; per-XCD
//   working set ~4MB = L2) and pairs heavy/light window classes per CU.

#define LL 2048
#define HH 8
#define EE 64
#define DD 64
#define RS (HH * EE)   // 512 floats between consecutive seq positions

typedef __attribute__((ext_vector_type(8))) short short8;
typedef __attribute__((ext_vector_type(4))) float floatx4;
typedef __attribute__((ext_vector_type(4))) _Float16 half4;
typedef __attribute__((ext_vector_type(2))) __fp16 fp16x2;   // cvt_pkrtz return type

static __device__ __forceinline__ unsigned f2bf(float f) {
    union { float f; unsigned u; } v; v.f = f;
    return (v.u + 0x7fff + ((v.u >> 16) & 1)) >> 16;   // RNE
}
static __device__ __forceinline__ unsigned pack2(float a, float b) {
    return f2bf(a) | (f2bf(b) << 16);
}
static __device__ __forceinline__ unsigned packh2(float a, float b) {
    union { fp16x2 h; unsigned u; } v;
    v.h = __builtin_amdgcn_cvt_pkrtz(a, b);
    return v.u;
}

// LDS layout (shorts): K bufs [0, 8192) = 2 x 4096; V^T bufs [8192, 17408) = 2 x 4608 (ld=72)
#define K_BUF(cu)  (sAll + (cu) * 4096)
#define V_BUF(cu)  (sAll + 8192 + (cu) * 4608)

__global__ __launch_bounds__(512, 4) void mwa_r9(
    const float* __restrict__ Q,
    const float* __restrict__ K,
    const float* __restrict__ V,
    float* __restrict__ O)
{
    const int tid  = threadIdx.x;
    const int lane = tid & 63;
    const int wv   = tid >> 6;          // 0..7, wave owns q-rows wv*16..+15
    const int quad = lane >> 4;
    const int l15  = lane & 15;

    // ---- task decode: heavy classes (w256/w128) in gid<256, light in gid>=256.
    //      gid&7 = (b&1)*4 + hb*2 + p  -> fixed per (b,h): slice pinned to one XCD;
    //      consecutive it are +16 in gid -> same XCD, co-timed -> L2-local overlap.
    //      Same-CU pair (gid, gid+256) = {w256+w32} or {w128+w64}.
    const int gid   = blockIdx.x;
    const int heavy = (gid >> 8) == 0;
    const int c     = gid & 255;
    const int it    = c >> 4;           // 0..15 (128-row i-tiles)
    const int rem   = c & 15;
    const int b     = rem >> 2;
    const int z     = rem & 3;
    const int hb    = z >> 1;
    const int p     = z & 1;
    const int h     = hb * 4 + (heavy ? (3 - p) : p);
    const int i0    = it << 7;
    const int w     = 32 << (h & 3);

    alignas(16) __shared__ short sAll[17408];   // 34816 B

    const float* Qb = Q + ((size_t)b * LL * HH + h) * EE;
    const float* Kb = K + ((size_t)b * LL * HH + h) * EE;
    const float* Vb = V + ((size_t)b * LL * HH + h) * DD;
    float*       Ob = O + ((size_t)b * LL * HH + h) * DD;

    // ---- stage Q (128 rows, bf16, ld=72, pre-scaled by 1/8) into pool; grab frags ----
    {
        const float sc = 0.125f;    // 2^-3: exact in bf16, folds softmax scale
        const int row = tid >> 2, cc = (tid & 3) << 4;
        const float4* src = (const float4*)(Qb + (size_t)(i0 + row) * RS + cc);
        float4 f0 = src[0], f1 = src[1], f2 = src[2], f3 = src[3];
        uint4 u0 = { pack2(sc*f0.x,sc*f0.y), pack2(sc*f0.z,sc*f0.w),
                     pack2(sc*f1.x,sc*f1.y), pack2(sc*f1.z,sc*f1.w) };
        uint4 u1 = { pack2(sc*f2.x,sc*f2.y), pack2(sc*f2.z,sc*f2.w),
                     pack2(sc*f3.x,sc*f3.y), pack2(sc*f3.z,sc*f3.w) };
        uint4* dst = (uint4*)&sAll[row * 72 + cc];   // 128*72 shorts = 18432 B < 34816 B
        dst[0] = u0; dst[1] = u1;
    }
    __syncthreads();
    short8 qf0, qf1;
    {
        const short* qp = &sAll[(wv * 16 + l15) * 72 + quad * 8];
        qf0 = *(const short8*)qp;
        qf1 = *(const short8*)(qp + 32);
    }
    __syncthreads();   // all Q-frag reads done before K/V staging overwrites

    const int jt_lo = max(0, i0 - w) >> 6;
    const int jt_hi = min(LL - 1, i0 + 127 + w) >> 6;

    // ---- stage first tile into buffer 0 (512 threads share one 64x64 tile) ----
    {
        const int j0 = jt_lo << 6;
        const int row = tid >> 3, cc = (tid & 7) << 3;       // 64 rows x 8 floats
        const float4* src = (const float4*)(Kb + (size_t)(j0 + row) * RS + cc);
        float4 f0 = src[0], f1 = src[1];
        float vv[8];
#pragma unroll
        for (int rr = 0; rr < 8; ++rr)
            vv[rr] = Vb[(size_t)(j0 + wv * 8 + rr) * RS + lane];

        uint4 u0 = { pack2(f0.x,f0.y), pack2(f0.z,f0.w), pack2(f1.x,f1.y), pack2(f1.z,f1.w) };
        const int jtw = row >> 4, l15w = row & 15, ks = cc >> 5, q0 = (cc >> 3) & 3;
        *(uint4*)&K_BUF(0)[(((jtw * 2 + ks) * 4 + q0) * 16 + l15w) * 8] = u0;

        uint4 w0 = { packh2(vv[0],vv[1]), packh2(vv[2],vv[3]),
                     packh2(vv[4],vv[5]), packh2(vv[6],vv[7]) };
        *(uint4*)&V_BUF(0)[lane * 72 + wv * 8] = w0;
    }
    __syncthreads();

    floatx4 acc[4] = {};
    float lsum = 0.f;
    const int iq = i0 + wv * 16 + l15;   // this lane's query row (q = l15 in S^T)

    for (int jt = jt_lo; jt <= jt_hi; ++jt) {
        const int cur = (jt - jt_lo) & 1;
        const int nxt = cur ^ 1;
        const bool more = jt < jt_hi;
        const int j0 = jt << 6;

        // ---- prefetch next tile into registers ----
        float4 kf0, kf1;
        float vv[8];
        const int rowp = tid >> 3, cp = (tid & 7) << 3;
        if (more) {
            const int jn = (jt + 1) << 6;
            const float4* src = (const float4*)(Kb + (size_t)(jn + rowp) * RS + cp);
            kf0 = src[0]; kf1 = src[1];
#pragma unroll
            for (int rr = 0; rr < 8; ++rr)
                vv[rr] = Vb[(size_t)(jn + wv * 8 + rr) * RS + lane];
        }

        // ---- S^T = K.Q^T (Q pre-scaled), exp -> P^T in registers ----
        const bool full = ((i0 + 127 - j0) <= w) && ((j0 + 63 - i0) <= w);
        half4 pf[4];
#pragma unroll
        for (int t4 = 0; t4 < 4; ++t4) {
            const short* kp = &K_BUF(cur)[1024 * t4 + 128 * quad + 8 * l15];
            short8 k0 = *(const short8*)kp;
            short8 k1 = *(const short8*)(kp + 512);
            floatx4 st = {};
            st = __builtin_amdgcn_mfma_f32_16x16x32_bf16(k0, qf0, st, 0, 0, 0);
            st = __builtin_amdgcn_mfma_f32_16x16x32_bf16(k1, qf1, st, 0, 0, 0);

            float pr[4];
            const int jb = j0 + t4 * 16 + quad * 4;
#pragma unroll
            for (int r = 0; r < 4; ++r) {
                float x = st[r];
                if (!full) {
                    const int di = iq - (jb + r);
                    x = (di <= w && di >= -w) ? x : -INFINITY;
                }
                pr[r] = __expf(x);
                lsum += pr[r];
            }
            union { half4 v; unsigned u[2]; } pu;
            pu.u[0] = packh2(pr[0], pr[1]);
            pu.u[1] = packh2(pr[2], pr[3]);
            pf[t4] = pu.v;
        }

        // ---- O += P.V (A = P regs, B = V^T LDS) ----
#pragma unroll
        for (int nt = 0; nt < 4; ++nt) {
            const short* vbase = &V_BUF(cur)[(nt * 16 + l15) * 72];
#pragma unroll
            for (int t4 = 0; t4 < 4; ++t4) {
                half4 vf = *(const half4*)(vbase + t4 * 16 + quad * 4);
                acc[nt] = __builtin_amdgcn_mfma_f32_16x16x16f16(pf[t4], vf, acc[nt], 0, 0, 0);
            }
        }

        // ---- write prefetched tile to the other buffer ----
        if (more) {
            uint4 u0 = { pack2(kf0.x,kf0.y), pack2(kf0.z,kf0.w),
                         pack2(kf1.x,kf1.y), pack2(kf1.z,kf1.w) };
            const int jtw = rowp >> 4, l15w = rowp & 15, ks = cp >> 5, q0 = (cp >> 3) & 3;
            *(uint4*)&K_BUF(nxt)[(((jtw * 2 + ks) * 4 + q0) * 16 + l15w) * 8] = u0;

            uint4 w0 = { packh2(vv[0],vv[1]), packh2(vv[2],vv[3]),
                         packh2(vv[4],vv[5]), packh2(vv[6],vv[7]) };
            *(uint4*)&V_BUF(nxt)[lane * 72 + wv * 8] = w0;
        }
        __syncthreads();
    }

    // ---- epilogue: finish l, normalize, store (per-wave, no merge) ----
    lsum += __shfl_xor(lsum, 16, 64);
    lsum += __shfl_xor(lsum, 32, 64);      // lane (q = l15): row-sum over all j
    float rinv[4];
#pragma unroll
    for (int r = 0; r < 4; ++r) {
        const float lr = __shfl(lsum, quad * 4 + r, 64);
        rinv[r] = 1.0f / lr;
    }
#pragma unroll
    for (int nt = 0; nt < 4; ++nt) {
#pragma unroll
        for (int r = 0; r < 4; ++r) {
            Ob[(size_t)(i0 + wv * 16 + quad * 4 + r) * RS + nt * 16 + l15]
                = acc[nt][r] * rinv[r];
        }
    }
}

extern "C" void kernel_launch(void* const* d_in, const int* in_sizes, int n_in,
                              void* d_out, int out_size, void* d_ws, size_t ws_size,
                              hipStream_t stream)
{
    const float* Q = (const float*)d_in[0];
    const float* K = (const float*)d_in[1];
    const float* V = (const float*)d_in[2];
    float* O = (float*)d_out;

    dim3 grid(512), block(512);
    hipLaunchKernelGGL(mwa_r9, grid, block, 0, stream, Q, K, V, O);
}

// Round 4
// 100.905 us; speedup vs baseline: 1.1616x; 1.0069x over previous
//
#include <hip/hip_runtime.h>
#include <math.h>

// MultiWindowAttention B=4,L=2048,H=8,E=D=64 fp32; w = 32<<(h&3).
// Round 10: 2-deep prefetch + per-t4 band-skip (fused QK->exp->PV).
//   Model from R8/R9 misses: per visit-round ~5700cy observed vs ~1500cy
//   compute + ~1000cy service -> unhidden load latency at the vmcnt drain
//   before the LDS staging write (only 2 lockstep blocks/CU, nothing to
//   overlap). Fix A: issue tile jt+2's global loads during tile jt's
//   compute (sets A/B, loop unrolled 2x, static reg names) so the wait
//   before writing tile jt+1 is on loads issued a full iteration ago.
//   Fix B: skip 16x16 S^T sub-tiles fully outside the band (wave-uniform
//   test on wv/t4) and fuse PV per t4 -> ~25-30% of MFMA/exp/V-read work
//   removed (exact: skipped blocks contribute exp(-inf)=0; accumulation
//   order per acc[nt] unchanged -> bit-identical).
//   Structure otherwise = R9: 128-row i-tiles, 8 waves, shared dbuf K/V,
//   (b,h)->XCD pinning, heavy/light class pairing per CU.

#define LL 2048
#define HH 8
#define EE 64
#define DD 64
#define RS (HH * EE)   // 512 floats between consecutive seq positions

typedef __attribute__((ext_vector_type(8))) short short8;
typedef __attribute__((ext_vector_type(4))) float floatx4;
typedef __attribute__((ext_vector_type(4))) _Float16 half4;
typedef __attribute__((ext_vector_type(2))) __fp16 fp16x2;   // cvt_pkrtz return type

static __device__ __forceinline__ unsigned f2bf(float f) {
    union { float f; unsigned u; } v; v.f = f;
    return (v.u + 0x7fff + ((v.u >> 16) & 1)) >> 16;   // RNE
}
static __device__ __forceinline__ unsigned pack2(float a, float b) {
    return f2bf(a) | (f2bf(b) << 16);
}
static __device__ __forceinline__ unsigned packh2(float a, float b) {
    union { fp16x2 h; unsigned u; } v;
    v.h = __builtin_amdgcn_cvt_pkrtz(a, b);
    return v.u;
}

// LDS layout (shorts): K bufs [0, 8192) = 2 x 4096; V^T bufs [8192, 17408) = 2 x 4608 (ld=72)
#define K_BUF(cu)  (sAll + (cu) * 4096)
#define V_BUF(cu)  (sAll + 8192 + (cu) * 4608)

// ---- per-t4 fused compute: S^T += K.Q^T, mask, exp, P.V -> acc ----
static __device__ __forceinline__ void compute_tile(
    int j0, const short* __restrict__ kbase, const short* __restrict__ vbase,
    int w, int qb, int iq, int quad, int l15,
    short8 qf0, short8 qf1, floatx4* __restrict__ acc, float& lsum)
{
#pragma unroll
    for (int t4 = 0; t4 < 4; ++t4) {
        const int jb = j0 + t4 * 16;
        // wave-uniform band test for the 16q x 16j block
        if (jb > qb + 15 + w || jb + 15 < qb - w) continue;
        const bool needMask = ((jb + 15 - qb) > w) || ((qb + 15 - jb) > w);

        const short* kp = kbase + 1024 * t4 + 128 * quad + 8 * l15;
        short8 k0 = *(const short8*)kp;
        short8 k1 = *(const short8*)(kp + 512);
        floatx4 st = {};
        st = __builtin_amdgcn_mfma_f32_16x16x32_bf16(k0, qf0, st, 0, 0, 0);
        st = __builtin_amdgcn_mfma_f32_16x16x32_bf16(k1, qf1, st, 0, 0, 0);

        float pr[4];
        const int jq = jb + quad * 4;
#pragma unroll
        for (int r = 0; r < 4; ++r) {
            float x = st[r];
            if (needMask) {
                const int di = iq - (jq + r);
                x = (di <= w && di >= -w) ? x : -INFINITY;
            }
            pr[r] = __expf(x);
            lsum += pr[r];
        }
        half4 pf;
        {
            union { half4 v; unsigned u[2]; } pu;
            pu.u[0] = packh2(pr[0], pr[1]);
            pu.u[1] = packh2(pr[2], pr[3]);
            pf = pu.v;
        }
#pragma unroll
        for (int nt = 0; nt < 4; ++nt) {
            half4 vf = *(const half4*)(vbase + (nt * 16 + l15) * 72 + t4 * 16 + quad * 4);
            acc[nt] = __builtin_amdgcn_mfma_f32_16x16x16f16(pf, vf, acc[nt], 0, 0, 0);
        }
    }
}

// issue global loads for tile at row jn (K: 2x float4, V: 8 scalar rows)
#define ISSUE(jn, kf0_, kf1_, vv_)                                              \
    {                                                                           \
        const float4* src_ = (const float4*)(Kb + (size_t)((jn) + rowp) * RS + cp); \
        kf0_ = src_[0]; kf1_ = src_[1];                                         \
        _Pragma("unroll")                                                       \
        for (int rr_ = 0; rr_ < 8; ++rr_)                                       \
            vv_[rr_] = Vb[(size_t)((jn) + wv * 8 + rr_) * RS + lane];           \
    }

// pack registers -> LDS buffer bufIdx (compiler inserts the vmcnt wait)
#define STAGE(bufIdx, kf0_, kf1_, vv_)                                          \
    {                                                                           \
        uint4 u0_ = { pack2(kf0_.x,kf0_.y), pack2(kf0_.z,kf0_.w),               \
                      pack2(kf1_.x,kf1_.y), pack2(kf1_.z,kf1_.w) };             \
        *(uint4*)&K_BUF(bufIdx)[kWoff] = u0_;                                   \
        uint4 w0_ = { packh2(vv_[0],vv_[1]), packh2(vv_[2],vv_[3]),             \
                      packh2(vv_[4],vv_[5]), packh2(vv_[6],vv_[7]) };           \
        *(uint4*)&V_BUF(bufIdx)[vWoff] = w0_;                                   \
    }

__global__ __launch_bounds__(512, 4) void mwa_r10(
    const float* __restrict__ Q,
    const float* __restrict__ K,
    const float* __restrict__ V,
    float* __restrict__ O)
{
    const int tid  = threadIdx.x;
    const int lane = tid & 63;
    const int wv   = tid >> 6;          // 0..7, wave owns q-rows wv*16..+15
    const int quad = lane >> 4;
    const int l15  = lane & 15;

    // ---- task decode (= R9): heavy classes in gid<256; gid&7 fixed per (b,h) ----
    const int gid   = blockIdx.x;
    const int heavy = (gid >> 8) == 0;
    const int c     = gid & 255;
    const int it    = c >> 4;           // 0..15 (128-row i-tiles)
    const int rem   = c & 15;
    const int b     = rem >> 2;
    const int z     = rem & 3;
    const int hb    = z >> 1;
    const int p     = z & 1;
    const int h     = hb * 4 + (heavy ? (3 - p) : p);
    const int i0    = it << 7;
    const int w     = 32 << (h & 3);

    alignas(16) __shared__ short sAll[17408];   // 34816 B

    const float* Qb = Q + ((size_t)b * LL * HH + h) * EE;
    const float* Kb = K + ((size_t)b * LL * HH + h) * EE;
    const float* Vb = V + ((size_t)b * LL * HH + h) * DD;
    float*       Ob = O + ((size_t)b * LL * HH + h) * DD;

    // ---- stage Q (128 rows, bf16, ld=72, pre-scaled by 1/8); grab frags ----
    {
        const float sc = 0.125f;    // 2^-3: exact in bf16, folds softmax scale
        const int row = tid >> 2, cc = (tid & 3) << 4;
        const float4* src = (const float4*)(Qb + (size_t)(i0 + row) * RS + cc);
        float4 f0 = src[0], f1 = src[1], f2 = src[2], f3 = src[3];
        uint4 u0 = { pack2(sc*f0.x,sc*f0.y), pack2(sc*f0.z,sc*f0.w),
                     pack2(sc*f1.x,sc*f1.y), pack2(sc*f1.z,sc*f1.w) };
        uint4 u1 = { pack2(sc*f2.x,sc*f2.y), pack2(sc*f2.z,sc*f2.w),
                     pack2(sc*f3.x,sc*f3.y), pack2(sc*f3.z,sc*f3.w) };
        uint4* dst = (uint4*)&sAll[row * 72 + cc];   // 18432 B scratch
        dst[0] = u0; dst[1] = u1;
    }
    __syncthreads();
    short8 qf0, qf1;
    {
        const short* qp = &sAll[(wv * 16 + l15) * 72 + quad * 8];
        qf0 = *(const short8*)qp;
        qf1 = *(const short8*)(qp + 32);
    }
    __syncthreads();   // Q-frag reads done before K/V staging overwrites

    const int jt_lo = max(0, i0 - w) >> 6;
    const int jt_hi = min(LL - 1, i0 + 127 + w) >> 6;
    const int n     = jt_hi - jt_lo + 1;    // 3..10

    const int rowp  = tid >> 3, cp = (tid & 7) << 3;   // staging coords (64 rows x 8 floats)
    const int jtw   = rowp >> 4, l15w = rowp & 15, ks = cp >> 5, q0w = (cp >> 3) & 3;
    const int kWoff = (((jtw * 2 + ks) * 4 + q0w) * 16 + l15w) * 8;
    const int vWoff = lane * 72 + wv * 8;

    // ---- prologue: tile 0 -> buf0; then issue tile 1 into set A ----
    float4 kA0, kA1; float vA[8];
    float4 kB0, kB1; float vB[8];
    ISSUE(jt_lo << 6, kA0, kA1, vA);
    STAGE(0, kA0, kA1, vA);
    __syncthreads();
    if (n > 1) ISSUE((jt_lo + 1) << 6, kA0, kA1, vA);

    floatx4 acc[4] = {};
    float lsum = 0.f;
    const int iq = i0 + wv * 16 + l15;   // this lane's query row (q = l15 in S^T)
    const int qb = i0 + wv * 16;         // wave's q-block base

    for (int s = 0; s < n; s += 2) {
        const int jt = jt_lo + s;
        // ---- even tile s: buf0; A holds tile s+1; issue s+2 -> B ----
        if (s + 2 < n) ISSUE((jt + 2) << 6, kB0, kB1, vB);
        compute_tile(jt << 6, K_BUF(0), V_BUF(0), w, qb, iq, quad, l15, qf0, qf1, acc, lsum);
        if (s + 1 < n) STAGE(1, kA0, kA1, vA);
        __syncthreads();

        if (s + 1 < n) {
            // ---- odd tile s+1: buf1; B holds tile s+2; issue s+3 -> A ----
            if (s + 3 < n) ISSUE((jt + 3) << 6, kA0, kA1, vA);
            compute_tile((jt + 1) << 6, K_BUF(1), V_BUF(1), w, qb, iq, quad, l15, qf0, qf1, acc, lsum);
            if (s + 2 < n) STAGE(0, kB0, kB1, vB);
            __syncthreads();
        }
    }

    // ---- epilogue: finish l, normalize, store (per-wave, no merge) ----
    lsum += __shfl_xor(lsum, 16, 64);
    lsum += __shfl_xor(lsum, 32, 64);      // lane (q = l15): row-sum over all j
    float rinv[4];
#pragma unroll
    for (int r = 0; r < 4; ++r) {
        const float lr = __shfl(lsum, quad * 4 + r, 64);
        rinv[r] = 1.0f / lr;
    }
#pragma unroll
    for (int nt = 0; nt < 4; ++nt) {
#pragma unroll
        for (int r = 0; r < 4; ++r) {
            Ob[(size_t)(i0 + wv * 16 + quad * 4 + r) * RS + nt * 16 + l15]
                = acc[nt][r] * rinv[r];
        }
    }
}

extern "C" void kernel_launch(void* const* d_in, const int* in_sizes, int n_in,
                              void* d_out, int out_size, void* d_ws, size_t ws_size,
                              hipStream_t stream)
{
    const float* Q = (const float*)d_in[0];
    const float* K = (const float*)d_in[1];
    const float* V = (const float*)d_in[2];
    float* O = (float*)d_out;

    dim3 grid(512), block(512);
    hipLaunchKernelGGL(mwa_r10, grid, block, 0, stream, Q, K, V, O);
}